// Round 16
// baseline (485.972 us; speedup 1.0000x reference)
//
#include <hip/hip_runtime.h>
#include <hip/hip_fp16.h>
#include <math.h>

#define Hc   128
#define Bc   512
#define Tc   64
#define NXc  518
#define NCELL (518*518)
#define NEV  (Bc*Tc)            // 32768 events
#define SWc  2

// ---------------- precompute kernels ----------------

__global__ void k_build(const float* __restrict__ feat, int* __restrict__ head,
                        int* __restrict__ nxt, int* __restrict__ cellxy) {
    int gid = blockIdx.x * 256 + threadIdx.x;
    if (gid >= NEV) return;
    int b = gid >> 6, t = gid & 63;
    int base = (b * Tc + t) * 4;
    int gx = (int)feat[base + 2] + SWc;
    int gy = (int)feat[base + 3] + SWc;
    gx = min(max(gx, 0), NXc - 1);
    gy = min(max(gy, 0), NXc - 1);
    int cell = gx * NXc + gy;
    int e = t * Bc + b;
    cellxy[e] = (gx << 16) | gy;
    int old = atomicExch(&head[cell], e);
    nxt[e] = old;
}

__global__ void k_resolve(const int* __restrict__ head, const int* __restrict__ nxt,
                          const int* __restrict__ cellxy, int* __restrict__ dep) {
    int gid = blockIdx.x * 256 + threadIdx.x;
    if (gid >= NEV * 25) return;
    int r = gid / 25, k = gid - r * 25;
    int t = r & 63, b = r >> 6;
    int e0 = t * Bc + b;
    int xy = cellxy[e0];
    int gx = xy >> 16, gy = xy & 0xffff;
    int cx = gx + (k / 5) - SWc, cy = gy + (k % 5) - SWc;
    cx = min(max(cx, 0), NXc - 1);
    cy = min(max(cy, 0), NXc - 1);
    int cell = cx * NXc + cy;
    int best = -1;
    for (int e = head[cell]; e >= 0; e = nxt[e])
        if ((e >> 9) < t && e > best) best = e;
    dep[r * 25 + k] = best;
}

// ---------------- fast math + cross-lane ----------------

#define LOG2E 1.4426950408889634f
__device__ __forceinline__ float fexp(float x)  { return __builtin_amdgcn_exp2f(x * LOG2E); }
__device__ __forceinline__ float fsig(float x)  { return __builtin_amdgcn_rcpf(1.f + fexp(-x)); }
__device__ __forceinline__ float ftanh(float x) { return 1.f - 2.f * __builtin_amdgcn_rcpf(1.f + fexp(2.f * x)); }

template <int CTRL>
__device__ __forceinline__ float dppadd(float x) {
    int t = __builtin_amdgcn_update_dpp(0, __float_as_int(x), CTRL, 0xF, 0xF, true);
    return x + __int_as_float(t);
}
template <int CTRL>
__device__ __forceinline__ float dppmax(float x) {
    int t = __builtin_amdgcn_update_dpp(0, __float_as_int(x), CTRL, 0xF, 0xF, true);
    return fmaxf(x, __int_as_float(t));
}
__device__ __forceinline__ float swz16(float x) {   // lane ^= 16 within 32-groups
    return __int_as_float(__builtin_amdgcn_ds_swizzle(__float_as_int(x), 0x401F));
}
__device__ __forceinline__ float redsum64(float d) {
    d = dppadd<0xB1>(d); d = dppadd<0x4E>(d);
    d = dppadd<0x141>(d); d = dppadd<0x140>(d);
    d += swz16(d);
    d += __shfl_xor(d, 32, 64);
    return d;
}
// sum within 8-lane groups (stages xor1, xor2, xor4-equiv) — proven sub-chain
__device__ __forceinline__ float redsum8(float d) {
    d = dppadd<0xB1>(d); d = dppadd<0x4E>(d); d = dppadd<0x141>(d);
    return d;
}

// LDS-only barrier: waits lgkmcnt(0), leaves global ops in flight.
__device__ __forceinline__ void barlds() {
    asm volatile("" ::: "memory");
    __builtin_amdgcn_s_waitcnt(0xC07F);   // vmcnt=63, expcnt=7, lgkmcnt=0
    __builtin_amdgcn_s_barrier();
    asm volatile("" ::: "memory");
}

__device__ __forceinline__ unsigned flagload(const unsigned* p) {
    return __hip_atomic_load(p, __ATOMIC_RELAXED, __HIP_MEMORY_SCOPE_AGENT);
}

// ---------------- main persistent dataflow kernel ----------------

constexpr int LDS_FLOATS = 256 + 1024 + 256 + 256 + 64 + 2048 + 512 + 16 + 256 + 128;
constexpr int LDS_BYTES  = LDS_FLOATS * 4;   // ~19.3 KB

__global__ void
__attribute__((amdgpu_flat_work_group_size(1024, 1024)))
__attribute__((amdgpu_waves_per_eu(4, 4)))
step_main(const float* __restrict__ feat, const float* __restrict__ Wih,
          const float* __restrict__ bih,  const float* __restrict__ Whh,
          const float* __restrict__ bhh,  const float* __restrict__ Wout,
          const float* __restrict__ bout, const int*   __restrict__ seq,
          const int*   __restrict__ dep,  float* __restrict__ vbuf,
          unsigned*    __restrict__ flags, float* __restrict__ dout) {
    extern __shared__ float lds[];
    float* hid   = lds;                      // 2*128
    float* g     = hid   + 256;              // 2*512 gate pre-acts (INTACT all step)
    float* gin   = g     + 1024;             // 2*128
    float* ctr   = gin   + 256;              // 2*128
    float* scor  = ctr   + 256;              // 2*32
    float* pmix  = scor  + 64;               // 16*128 W_out partials
    float* catL  = pmix  + 2048;             // 2*256 cat=[mix,q]
    float* fxy   = catL  + 512;              // 2 parities * 8
    float* updL  = fxy   + 16;               // 2*128 staged vbuf payload
    int*   depv  = (int*)(updL + 256);       // 2 parities * 64 (50 used)

    const int tid  = threadIdx.x;            // 0..1023
    const int blk  = blockIdx.x;
    const int lane = tid & 63;
    const int w    = tid >> 6;               // wave 0..15
    const int wj   = w >> 3;                 // chain of this wave
    const int ww   = w & 7;                  // wave-within-chain

    // ---- W_hh: 4 rows x 16 interleaved cols per thread (64 regs) ----
    const int grp = tid >> 3;                // global row group: rows 4*grp..4*grp+3
    const int s   = tid & 7;                 // col slice: f4 indices s+8i, i=0..3
    float4 wrr[4][4];                        // [row][i] — static index only (rule #20)
    {
        const float4* wb = (const float4*)Whh;    // 32 f4 per row
        #pragma unroll
        for (int r = 0; r < 4; ++r)
            #pragma unroll
            for (int i = 0; i < 4; ++i)
                wrr[r][i] = wb[(size_t)(4 * grp + r) * 32 + s + 8 * i];
    }
    #pragma unroll
    for (int r = 0; r < 4; ++r)
        #pragma unroll
        for (int i = 0; i < 4; ++i)
            asm volatile("" : "+v"(wrr[r][i].x), "+v"(wrr[r][i].y),
                              "+v"(wrr[r][i].z), "+v"(wrr[r][i].w));

    const int jwl = s >> 2;                  // chain this lane publishes
    const int rwl = 4 * grp + (s & 3);       // row this lane publishes
    const float bihr = bih[rwl], bhhr = bhh[rwl];
    const float wihA = Wih[rwl * 2 + 0], wihB = Wih[rwl * 2 + 1];
    const int chunk = rwl >> 7;

    // ---- W_out: 32 cols as 16 packed half2 regs per thread ----
    const int oo7 = tid & 127, rep7 = tid >> 7;
    unsigned wo[16];                          // static index only
    {
        const float* wrow = Wout + (size_t)oo7 * 256 + rep7 * 32;
        #pragma unroll
        for (int m = 0; m < 16; ++m) {
            __half2 hh = __floats2half2_rn(wrow[2 * m], wrow[2 * m + 1]);
            unsigned u; __builtin_memcpy(&u, &hh, 4);
            wo[m] = u;
            asm volatile("" : "+v"(wo[m]));
        }
    }
    const float boutr = bout[oo7];

    if (tid < 256) hid[tid] = 0.f;
    if (tid < 8) { int j = tid >> 2, c = tid & 3;
                   fxy[tid] = feat[((size_t)(blk * 2 + j) * Tc + 0) * 4 + c]; }
    if (tid < 50) {
        int j = (tid >= 25), k = tid - j * 25;
        depv[tid] = dep[(((size_t)(blk * 2 + j)) * Tc + 0) * 25 + k];
    }
    const int s0 = max(seq[blk * 2 + 0], 1) - 1;
    const int s1 = max(seq[blk * 2 + 1], 1) - 1;
    __syncthreads();

    const float NEG_INF = -__builtin_inff();

    for (int t = 0; t < Tc; ++t) {
        const float* fx = fxy + (t & 1) * 8;
        int* depvCur = depv + (t & 1) * 64;
        int* depvNxt = depv + ((t + 1) & 1) * 64;

        // ==== P1: publish(t-1) + flag prefetch + gh GEMV + prefetch + spin + loads ====
        if (t > 0 && (w == 0 || w == 2)) {
            int j = w >> 1;
            float2 u = *(const float2*)&updL[j * 128 + 2 * lane];
            unsigned long long raw; __builtin_memcpy(&raw, &u, 8);
            __hip_atomic_store((unsigned long long*)(vbuf +
                ((size_t)((t - 1) * Bc + blk * 2 + j)) * Hc + 2 * lane),
                raw, __ATOMIC_RELAXED, __HIP_MEMORY_SCOPE_AGENT);
        }
        const int mye = (lane < 25) ? depvCur[wj * 25 + lane] : -1;
        unsigned fpre = 1u;
        if (mye >= 0)
            fpre = flagload(&flags[mye]);

        // 4-row x 16-interleaved-col GEMV (h-reads: 8 b128, conflict-free)
        float acc[2][4];
        #pragma unroll
        for (int j = 0; j < 2; ++j) {
            const float4* hp = (const float4*)(hid + j * 128);
            float4 h0 = hp[s], h1 = hp[s + 8], h2 = hp[s + 16], h3 = hp[s + 24];
            #pragma unroll
            for (int r = 0; r < 4; ++r) {
                float4 w0 = wrr[r][0], w1 = wrr[r][1], w2 = wrr[r][2], w3 = wrr[r][3];
                float a = 0.f;
                a = fmaf(w0.x, h0.x, fmaf(w0.y, h0.y, fmaf(w0.z, h0.z, fmaf(w0.w, h0.w, a))));
                a = fmaf(w1.x, h1.x, fmaf(w1.y, h1.y, fmaf(w1.z, h1.z, fmaf(w1.w, h1.w, a))));
                a = fmaf(w2.x, h2.x, fmaf(w2.y, h2.y, fmaf(w2.z, h2.z, fmaf(w2.w, h2.w, a))));
                a = fmaf(w3.x, h3.x, fmaf(w3.y, h3.y, fmaf(w3.z, h3.z, fmaf(w3.w, h3.w, a))));
                acc[j][r] = a;
            }
        }
        #pragma unroll
        for (int j = 0; j < 2; ++j)
            #pragma unroll
            for (int r = 0; r < 4; ++r)
                acc[j][r] = redsum8(acc[j][r]);
        {
            int sb = s & 3;
            float m0 = (sb == 0) ? acc[0][0] : (sb == 1) ? acc[0][1]
                     : (sb == 2) ? acc[0][2] : acc[0][3];
            float m1 = (sb == 0) ? acc[1][0] : (sb == 1) ? acc[1][1]
                     : (sb == 2) ? acc[1][2] : acc[1][3];
            float mine = jwl ? m1 : m0;
            float gi = fmaf(wihA, fx[jwl * 4 + 0], wihB * fx[jwl * 4 + 1]);
            g[jwl * 512 + rwl] = mine + bhhr + ((chunk == 2) ? 0.f : (gi + bihr));
            if (chunk == 2) gin[jwl * 128 + (rwl & 127)] = gi + bihr;
        }
        if (tid >= 512 && tid < 562 && t + 1 < Tc) {
            int idx = tid - 512;
            int j = (idx >= 25), k = idx - j * 25;
            depvNxt[idx] = dep[(((size_t)(blk * 2 + j)) * Tc + (t + 1)) * 25 + k];
        }
        if (tid >= 960 && tid < 968 && t + 1 < Tc) {
            int idx = tid - 960, j = idx >> 2, c = idx & 3;
            fxy[((t + 1) & 1) * 8 + idx] =
                feat[((size_t)(blk * 2 + j) * Tc + (t + 1)) * 4 + c];
        }
        if (t > 0 && (w == 0 || w == 2)) {   // publish-ack arrived during GEMV -> ~free
            asm volatile("s_waitcnt vmcnt(0)" ::: "memory");
            if (lane == 0)
                __hip_atomic_store(&flags[(t - 1) * Bc + blk * 2 + (w >> 1)], 1u,
                                   __ATOMIC_RELAXED, __HIP_MEMORY_SCOPE_AGENT);
        }
        {
            bool pend = (mye >= 0) && (fpre == 0u);
            while (__any(pend)) {
                if (pend && flagload(&flags[mye]) != 0u)
                    pend = false;
                if (__any(pend)) __builtin_amdgcn_s_sleep(1);
            }
        }
        asm volatile("" ::: "memory");       // value loads strictly after flags
        float2 valk[4];
        int    evk[4];
        #pragma unroll
        for (int kk = 0; kk < 4; ++kk) {
            int k = ww + 8 * kk;
            evk[kk] = (k < 25) ? depvCur[wj * 25 + k] : -1;
            valk[kk] = make_float2(0.f, 0.f);
            if (evk[kk] >= 0)
                valk[kk] = *(const float2*)(vbuf + (size_t)evk[kk] * Hc + 2 * lane);
        }
        barlds();

        // ==== P4: per-wave q + catL q-half + mix-half zero + ctr + scores ====
        float q0, q1;
        {
            float2 gr2 = *(const float2*)&g[wj * 512 + 2 * lane];
            float2 gn2 = *(const float2*)&g[wj * 512 + 256 + 2 * lane];
            float2 gi2 = *(const float2*)&gin[wj * 128 + 2 * lane];
            q0 = ftanh(gi2.x + fsig(gr2.x) * gn2.x);
            q1 = ftanh(gi2.y + fsig(gr2.y) * gn2.y);
        }
        if (ww == 0) *(float2*)&catL[wj * 256 + 128 + 2 * lane] = make_float2(q0, q1);
        if (ww == 1) *(float2*)&catL[wj * 256 + 2 * lane] = make_float2(0.f, 0.f);
        if (ww == 4)   // owns k=12 (kk=1): center context
            *(float2*)&ctr[wj * 128 + 2 * lane] =
                (evk[1] >= 0) ? valk[1] : make_float2(0.f, 0.f);
        #pragma unroll
        for (int kk = 0; kk < 4; ++kk) {
            int k = ww + 8 * kk;
            if (k < 25) {
                float sc;
                if (evk[kk] >= 0) {
                    float d = fmaf(valk[kk].x, q0, valk[kk].y * q1);
                    d = redsum64(d);
                    sc = (d == 0.f) ? NEG_INF : d;
                } else sc = NEG_INF;
                if (lane == 0) scor[wj * 32 + k] = sc;
            }
        }
        barlds();

        // ==== P56: per-wave softmax (DPP) + mix via ds_add into catL ====
        {
            int k2 = lane & 31;
            float v = (k2 < 25) ? scor[wj * 32 + k2] : NEG_INF;
            float m = v;
            m = dppmax<0xB1>(m); m = dppmax<0x4E>(m);
            m = dppmax<0x141>(m); m = dppmax<0x140>(m);
            m = fmaxf(m, swz16(m));
            float a = 0.f;
            if (m != NEG_INF) {
                float p = (v == NEG_INF) ? 0.f : fexp(v - m);
                float ssum = p;
                ssum = dppadd<0xB1>(ssum); ssum = dppadd<0x4E>(ssum);
                ssum = dppadd<0x141>(ssum); ssum = dppadd<0x140>(ssum);
                ssum += swz16(ssum);
                a = p / ssum;
            }
            if ((evk[0] >= 0) | (evk[1] >= 0) | (evk[2] >= 0) | (evk[3] >= 0)) {
                float pm0 = 0.f, pm1 = 0.f;
                #pragma unroll
                for (int kk = 0; kk < 4; ++kk) {
                    int k = ww + 8 * kk;
                    if (k < 25 && evk[kk] >= 0) {
                        float ak = __int_as_float(
                            __builtin_amdgcn_readlane(__float_as_int(a), k));
                        pm0 = fmaf(ak, valk[kk].x, pm0);
                        pm1 = fmaf(ak, valk[kk].y, pm1);
                    }
                }
                atomicAdd(&catL[wj * 256 + 2 * lane],     pm0);
                atomicAdd(&catL[wj * 256 + 2 * lane + 1], pm1);
            }
        }
        barlds();

        // ==== P7b: W_out dots (weights in regs; cat b128 broadcast reads) ====
        {
            const float4* c04 = (const float4*)(catL + rep7 * 32);
            const float4* c14 = (const float4*)(catL + 256 + rep7 * 32);
            float acc0 = 0.f, acc1 = 0.f;
            #pragma unroll
            for (int i = 0; i < 8; ++i) {
                unsigned ua = wo[2 * i], ub = wo[2 * i + 1];
                __half2 wa, wb2;
                __builtin_memcpy(&wa, &ua, 4); __builtin_memcpy(&wb2, &ub, 4);
                float wx = __low2float(wa), wy = __high2float(wa);
                float wz = __low2float(wb2), wv = __high2float(wb2);
                float4 c0 = c04[i], c1 = c14[i];
                acc0 = fmaf(wx, c0.x, fmaf(wy, c0.y, fmaf(wz, c0.z, fmaf(wv, c0.w, acc0))));
                acc1 = fmaf(wx, c1.x, fmaf(wy, c1.y, fmaf(wz, c1.z, fmaf(wv, c1.w, acc1))));
            }
            pmix[rep7 * 128 + oo7]       = acc0;
            pmix[(8 + rep7) * 128 + oo7] = acc1;
        }
        barlds();

        // ==== P7c: epilogue (full gate recompute from intact g) + updL stage ====
        if (tid < 256) {
            int j = tid >> 7, h = tid & 127;
            float tot = boutr;
            #pragma unroll
            for (int p = 0; p < 8; ++p) tot += pmix[(j * 8 + p) * 128 + h];
            float at = ftanh(tot);
            float gr = g[j * 512 + h],       gu = g[j * 512 + 128 + h];
            float gn = g[j * 512 + 256 + h], gs = g[j * 512 + 384 + h];
            float rr = fsig(gr), uu = fsig(gu), ss = fsig(gs);
            float nn = ftanh(gin[j * 128 + h] + rr * gn);
            float hv = hid[j * 128 + h];
            float curr = fmaf(ss, at, nn);
            float outv = curr + uu * (hv - curr);
            hid[j * 128 + h] = outv;
            if (t < Tc - 1)
                updL[tid] = fmaf(ss, ctr[j * 128 + h], (1.f - ss) * outv);
            int sj = (j == 0) ? s0 : s1;
            if (sj == t) dout[(size_t)(blk * 2 + j) * Hc + h] = outv;
        }
        barlds();
    }
}

// ---------------- host launch ----------------

extern "C" void kernel_launch(void* const* d_in, const int* in_sizes, int n_in,
                              void* d_out, int out_size, void* d_ws, size_t ws_size,
                              hipStream_t stream) {
    const float* feat = (const float*)d_in[0];
    const float* Wih  = (const float*)d_in[1];
    const float* bih  = (const float*)d_in[2];
    const float* Whh  = (const float*)d_in[3];
    const float* bhh  = (const float*)d_in[4];
    const float* Wout = (const float*)d_in[5];
    const float* bout = (const float*)d_in[6];
    const int*   seq  = (const int*)d_in[7];

    char* ws = (char*)d_ws;
    size_t off = 0;
    auto carve = [&](size_t bytes) { char* p = ws + off; off += (bytes + 511) & ~(size_t)511; return p; };
    float*    vbuf   = (float*)   carve((size_t)NEV * Hc * 4);
    int*      head   = (int*)     carve((size_t)NCELL * 4);
    int*      nxt    = (int*)     carve((size_t)NEV * 4);
    int*      cellxy = (int*)     carve((size_t)NEV * 4);
    int*      dep    = (int*)     carve((size_t)NEV * 25 * 4);
    unsigned* flags  = (unsigned*)carve((size_t)NEV * 4);

    hipMemsetAsync(head, 0xFF, (size_t)NCELL * 4, stream);
    hipMemsetAsync(flags, 0, (size_t)NEV * 4, stream);

    k_build<<<(NEV + 255) / 256, 256, 0, stream>>>(feat, head, nxt, cellxy);
    k_resolve<<<(NEV * 25 + 255) / 256, 256, 0, stream>>>(head, nxt, cellxy, dep);

    hipFuncSetAttribute((const void*)step_main,
                        hipFuncAttributeMaxDynamicSharedMemorySize, LDS_BYTES);
    step_main<<<256, 1024, LDS_BYTES, stream>>>(feat, Wih, bih, Whh, bhh, Wout, bout,
                                                seq, dep, vbuf, flags, (float*)d_out);
}

// Round 17
// 427.138 us; speedup vs baseline: 1.1377x; 1.1377x over previous
//
#include <hip/hip_runtime.h>
#include <hip/hip_fp16.h>
#include <math.h>

#define Hc   128
#define Bc   512
#define Tc   64
#define NXc  518
#define NCELL (518*518)
#define NEV  (Bc*Tc)            // 32768 events
#define SWc  2

// ---------------- precompute kernels ----------------

__global__ void k_build(const float* __restrict__ feat, int* __restrict__ head,
                        int* __restrict__ nxt, int* __restrict__ cellxy) {
    int gid = blockIdx.x * 256 + threadIdx.x;
    if (gid >= NEV) return;
    int b = gid >> 6, t = gid & 63;
    int base = (b * Tc + t) * 4;
    int gx = (int)feat[base + 2] + SWc;
    int gy = (int)feat[base + 3] + SWc;
    gx = min(max(gx, 0), NXc - 1);
    gy = min(max(gy, 0), NXc - 1);
    int cell = gx * NXc + gy;
    int e = t * Bc + b;
    cellxy[e] = (gx << 16) | gy;
    int old = atomicExch(&head[cell], e);
    nxt[e] = old;
}

__global__ void k_resolve(const int* __restrict__ head, const int* __restrict__ nxt,
                          const int* __restrict__ cellxy, int* __restrict__ dep) {
    int gid = blockIdx.x * 256 + threadIdx.x;
    if (gid >= NEV * 25) return;
    int r = gid / 25, k = gid - r * 25;
    int t = r & 63, b = r >> 6;
    int e0 = t * Bc + b;
    int xy = cellxy[e0];
    int gx = xy >> 16, gy = xy & 0xffff;
    int cx = gx + (k / 5) - SWc, cy = gy + (k % 5) - SWc;
    cx = min(max(cx, 0), NXc - 1);
    cy = min(max(cy, 0), NXc - 1);
    int cell = cx * NXc + cy;
    int best = -1;
    for (int e = head[cell]; e >= 0; e = nxt[e])
        if ((e >> 9) < t && e > best) best = e;
    dep[r * 25 + k] = best;
}

// ---------------- fast math + cross-lane ----------------

#define LOG2E 1.4426950408889634f
__device__ __forceinline__ float fexp(float x)  { return __builtin_amdgcn_exp2f(x * LOG2E); }
__device__ __forceinline__ float fsig(float x)  { return __builtin_amdgcn_rcpf(1.f + fexp(-x)); }
__device__ __forceinline__ float ftanh(float x) { return 1.f - 2.f * __builtin_amdgcn_rcpf(1.f + fexp(2.f * x)); }

template <int CTRL>
__device__ __forceinline__ float dppadd(float x) {
    int t = __builtin_amdgcn_update_dpp(0, __float_as_int(x), CTRL, 0xF, 0xF, true);
    return x + __int_as_float(t);
}
template <int CTRL>
__device__ __forceinline__ float dppmax(float x) {
    int t = __builtin_amdgcn_update_dpp(0, __float_as_int(x), CTRL, 0xF, 0xF, true);
    return fmaxf(x, __int_as_float(t));
}
__device__ __forceinline__ float swz16(float x) {   // lane ^= 16 within 32-groups
    return __int_as_float(__builtin_amdgcn_ds_swizzle(__float_as_int(x), 0x401F));
}
__device__ __forceinline__ float redsum64(float d) {
    d = dppadd<0xB1>(d); d = dppadd<0x4E>(d);
    d = dppadd<0x141>(d); d = dppadd<0x140>(d);
    d += swz16(d);
    d += __shfl_xor(d, 32, 64);
    return d;
}

// LDS-only barrier: waits lgkmcnt(0), leaves global ops in flight.
__device__ __forceinline__ void barlds() {
    asm volatile("" ::: "memory");
    __builtin_amdgcn_s_waitcnt(0xC07F);   // vmcnt=63, expcnt=7, lgkmcnt=0
    __builtin_amdgcn_s_barrier();
    asm volatile("" ::: "memory");
}

__device__ __forceinline__ unsigned flagload(const unsigned* p) {
    return __hip_atomic_load(p, __ATOMIC_RELAXED, __HIP_MEMORY_SCOPE_AGENT);
}

// ---------------- main persistent dataflow kernel ----------------

constexpr int LDS_FLOATS = 256 + 1024 + 256 + 256 + 256 + 64 + 2048 + 512 + 16 + 256 + 128;
constexpr int LDS_BYTES  = LDS_FLOATS * 4;   // ~20.4 KB

__global__ void
__attribute__((amdgpu_flat_work_group_size(1024, 1024)))
__attribute__((amdgpu_waves_per_eu(4, 4)))
step_main(const float* __restrict__ feat, const float* __restrict__ Wih,
          const float* __restrict__ bih,  const float* __restrict__ Whh,
          const float* __restrict__ bhh,  const float* __restrict__ Wout,
          const float* __restrict__ bout, const int*   __restrict__ seq,
          const int*   __restrict__ dep,  float* __restrict__ vbuf,
          unsigned*    __restrict__ flags, float* __restrict__ dout) {
    extern __shared__ float lds[];
    float* hid   = lds;                      // 2*128
    float* g     = hid   + 256;              // 2*512 gate pre-acts (INTACT all step)
    float* gin   = g     + 1024;             // 2*128
    float* ctr   = gin   + 256;              // 2*128
    float* qvL   = ctr   + 256;              // 2*128
    float* scor  = qvL   + 256;              // 2*32
    float* pmix  = scor  + 64;               // 16*128 per-wave mix partials
    float* catL  = pmix  + 2048;             // 2*256 cat=[mix,q]
    float* fxy   = catL  + 512;              // 2 parities * 8
    float* updL  = fxy   + 16;               // 2*128 staged vbuf payload
    int*   depv  = (int*)(updL + 256);       // 2 parities * 64 (50 used)

    const int tid  = threadIdx.x;            // 0..1023
    const int blk  = blockIdx.x;
    const int lane = tid & 63;
    const int w    = tid >> 6;               // wave 0..15
    const int wj   = w >> 3;                 // chain of this wave
    const int ww   = w & 7;                  // wave-within-chain

    // ---- W_hh: 2 rows x 32 interleaved cols per thread (64 regs) ----
    const int rp = tid >> 2;
    const int q  = tid & 3;
    const int r0 = 2 * rp, r1 = 2 * rp + 1;
    float4 wr0[8], wr1[8];                   // statically indexed only (rule #20)
    {
        const float4* w0 = (const float4*)(Whh + (size_t)r0 * Hc);
        const float4* w1 = (const float4*)(Whh + (size_t)r1 * Hc);
        #pragma unroll
        for (int i = 0; i < 8; ++i) { wr0[i] = w0[q + 4 * i]; wr1[i] = w1[q + 4 * i]; }
    }
    #pragma unroll
    for (int i = 0; i < 8; ++i) {
        asm volatile("" : "+v"(wr0[i].x), "+v"(wr0[i].y), "+v"(wr0[i].z), "+v"(wr0[i].w));
        asm volatile("" : "+v"(wr1[i].x), "+v"(wr1[i].y), "+v"(wr1[i].z), "+v"(wr1[i].w));
    }
    const int jw = q & 1;
    const int rw = r0 + (q >> 1);
    const float bihr = bih[rw], bhhr = bhh[rw];
    const float wihA = Wih[rw * 2 + 0], wihB = Wih[rw * 2 + 1];
    const int chunk = rw >> 7;

    // ---- W_out: row oo = 8*w + (lane&7), col-slice p = lane>>3 (32 cols) ----
    const int oi = lane & 7, p = lane >> 3;
    const int oo = 8 * w + oi;               // 0..127
    unsigned wo[16];                         // 16 packed half2 (static index only)
    {
        const float* wrow = Wout + (size_t)oo * 256 + p * 32;
        #pragma unroll
        for (int m = 0; m < 16; ++m) {
            __half2 hh = __floats2half2_rn(wrow[2 * m], wrow[2 * m + 1]);
            unsigned u; __builtin_memcpy(&u, &hh, 4);
            wo[m] = u;
            asm volatile("" : "+v"(wo[m]));
        }
    }
    const float boutr = bout[oo];

    if (tid < 256) hid[tid] = 0.f;
    if (tid < 8) { int j = tid >> 2, c = tid & 3;
                   fxy[tid] = feat[((size_t)(blk * 2 + j) * Tc + 0) * 4 + c]; }
    if (tid < 50) {
        int j = (tid >= 25), k = tid - j * 25;
        depv[tid] = dep[(((size_t)(blk * 2 + j)) * Tc + 0) * 25 + k];
    }
    const int s0 = max(seq[blk * 2 + 0], 1) - 1;
    const int s1 = max(seq[blk * 2 + 1], 1) - 1;
    __syncthreads();

    const float NEG_INF = -__builtin_inff();

    for (int t = 0; t < Tc; ++t) {
        const float* fx = fxy + (t & 1) * 8;
        int* depvCur = depv + (t & 1) * 64;
        int* depvNxt = depv + ((t + 1) & 1) * 64;

        // ==== P1: publish(t-1) + flag prefetch + gh GEMV + prefetch + spin + loads ====
        if (t > 0 && (w == 0 || w == 2)) {
            int j = w >> 1;
            float2 u = *(const float2*)&updL[j * 128 + 2 * lane];
            unsigned long long raw; __builtin_memcpy(&raw, &u, 8);
            __hip_atomic_store((unsigned long long*)(vbuf +
                ((size_t)((t - 1) * Bc + blk * 2 + j)) * Hc + 2 * lane),
                raw, __ATOMIC_RELAXED, __HIP_MEMORY_SCOPE_AGENT);
        }
        const int mye = (lane < 25) ? depvCur[wj * 25 + lane] : -1;
        unsigned fpre = 1u;
        if (mye >= 0)
            fpre = flagload(&flags[mye]);

        float a00 = 0.f, a01 = 0.f, a10 = 0.f, a11 = 0.f;
        {
            const float4* h0 = (const float4*)hid;
            const float4* h1 = (const float4*)(hid + 128);
            #pragma unroll
            for (int i = 0; i < 8; ++i) {
                float4 hv0 = h0[q + 4 * i], hv1 = h1[q + 4 * i];
                float4 w0 = wr0[i], w1 = wr1[i];
                a00 = fmaf(w0.x, hv0.x, fmaf(w0.y, hv0.y, fmaf(w0.z, hv0.z, fmaf(w0.w, hv0.w, a00))));
                a01 = fmaf(w1.x, hv0.x, fmaf(w1.y, hv0.y, fmaf(w1.z, hv0.z, fmaf(w1.w, hv0.w, a01))));
                a10 = fmaf(w0.x, hv1.x, fmaf(w0.y, hv1.y, fmaf(w0.z, hv1.z, fmaf(w0.w, hv1.w, a10))));
                a11 = fmaf(w1.x, hv1.x, fmaf(w1.y, hv1.y, fmaf(w1.z, hv1.z, fmaf(w1.w, hv1.w, a11))));
            }
        }
        a00 = dppadd<0x4E>(dppadd<0xB1>(a00));
        a01 = dppadd<0x4E>(dppadd<0xB1>(a01));
        a10 = dppadd<0x4E>(dppadd<0xB1>(a10));
        a11 = dppadd<0x4E>(dppadd<0xB1>(a11));
        {
            float mine = (q & 1) ? ((q >> 1) ? a11 : a10) : ((q >> 1) ? a01 : a00);
            float gi  = fmaf(wihA, fx[jw * 4 + 0], wihB * fx[jw * 4 + 1]);
            g[jw * 512 + rw] = mine + bhhr + ((chunk == 2) ? 0.f : (gi + bihr));
            if (chunk == 2) gin[jw * 128 + (rw & 127)] = gi + bihr;
        }
        if (tid >= 512 && tid < 562 && t + 1 < Tc) {
            int idx = tid - 512;
            int j = (idx >= 25), k = idx - j * 25;
            depvNxt[idx] = dep[(((size_t)(blk * 2 + j)) * Tc + (t + 1)) * 25 + k];
        }
        if (tid >= 960 && tid < 968 && t + 1 < Tc) {
            int idx = tid - 960, j = idx >> 2, c = idx & 3;
            fxy[((t + 1) & 1) * 8 + idx] =
                feat[((size_t)(blk * 2 + j) * Tc + (t + 1)) * 4 + c];
        }
        if (t > 0 && (w == 0 || w == 2)) {   // publish-ack arrived during GEMV -> ~free
            asm volatile("s_waitcnt vmcnt(0)" ::: "memory");
            if (lane == 0)
                __hip_atomic_store(&flags[(t - 1) * Bc + blk * 2 + (w >> 1)], 1u,
                                   __ATOMIC_RELAXED, __HIP_MEMORY_SCOPE_AGENT);
        }
        {
            bool pend = (mye >= 0) && (fpre == 0u);
            while (__any(pend)) {
                if (pend && flagload(&flags[mye]) != 0u)
                    pend = false;
                if (__any(pend)) __builtin_amdgcn_s_sleep(1);
            }
        }
        asm volatile("" ::: "memory");       // value loads strictly after flags
        float2 valk[4];
        int    evk[4];
        #pragma unroll
        for (int kk = 0; kk < 4; ++kk) {
            int k = ww + 8 * kk;
            evk[kk] = (k < 25) ? depvCur[wj * 25 + k] : -1;
            valk[kk] = make_float2(0.f, 0.f);
            if (evk[kk] >= 0)
                valk[kk] = *(const float2*)(vbuf + (size_t)evk[kk] * Hc + 2 * lane);
        }
        barlds();

        // ==== P4: per-wave q + qvL + ctr + scores (DPP reduce) ====
        float q0, q1;
        {
            float2 gr2 = *(const float2*)&g[wj * 512 + 2 * lane];
            float2 gn2 = *(const float2*)&g[wj * 512 + 256 + 2 * lane];
            float2 gi2 = *(const float2*)&gin[wj * 128 + 2 * lane];
            q0 = ftanh(gi2.x + fsig(gr2.x) * gn2.x);
            q1 = ftanh(gi2.y + fsig(gr2.y) * gn2.y);
        }
        if (ww == 0) *(float2*)&qvL[wj * 128 + 2 * lane] = make_float2(q0, q1);
        if (ww == 4)   // owns k=12 (kk=1): center context
            *(float2*)&ctr[wj * 128 + 2 * lane] =
                (evk[1] >= 0) ? valk[1] : make_float2(0.f, 0.f);
        #pragma unroll
        for (int kk = 0; kk < 4; ++kk) {
            int k = ww + 8 * kk;
            if (k < 25) {
                float sc;
                if (evk[kk] >= 0) {
                    float d = fmaf(valk[kk].x, q0, valk[kk].y * q1);
                    d = redsum64(d);
                    sc = (d == 0.f) ? NEG_INF : d;
                } else sc = NEG_INF;
                if (lane == 0) scor[wj * 32 + k] = sc;
            }
        }
        barlds();

        // ==== P56: per-wave softmax (DPP) + per-wave mix partials ====
        {
            int k2 = lane & 31;
            float v = (k2 < 25) ? scor[wj * 32 + k2] : NEG_INF;
            float m = v;
            m = dppmax<0xB1>(m); m = dppmax<0x4E>(m);
            m = dppmax<0x141>(m); m = dppmax<0x140>(m);
            m = fmaxf(m, swz16(m));
            float a = 0.f;
            if (m != NEG_INF) {
                float pr = (v == NEG_INF) ? 0.f : fexp(v - m);
                float s = pr;
                s = dppadd<0xB1>(s); s = dppadd<0x4E>(s);
                s = dppadd<0x141>(s); s = dppadd<0x140>(s);
                s += swz16(s);
                a = pr / s;
            }
            float pm0 = 0.f, pm1 = 0.f;
            #pragma unroll
            for (int kk = 0; kk < 4; ++kk) {
                int k = ww + 8 * kk;
                if (k < 25 && evk[kk] >= 0) {
                    float ak = __int_as_float(
                        __builtin_amdgcn_readlane(__float_as_int(a), k));
                    pm0 = fmaf(ak, valk[kk].x, pm0);
                    pm1 = fmaf(ak, valk[kk].y, pm1);
                }
            }
            *(float2*)&pmix[(wj * 8 + ww) * 128 + 2 * lane] = make_float2(pm0, pm1);
        }
        barlds();

        // ==== P7a: cat = [mix, q] into catL ====
        if (tid < 256) {
            int j = tid >> 7, h = tid & 127;
            float mix = 0.f;
            #pragma unroll
            for (int pp = 0; pp < 8; ++pp) mix += pmix[(j * 8 + pp) * 128 + h];
            catL[j * 256 + h] = mix;
            catL[j * 256 + 128 + h] = qvL[j * 128 + h];
        }
        barlds();

        // ==== P7: FUSED W_out GEMV (weights in regs) + DPP reduce + epilogue ====
        {
            const float4* cat4 = (const float4*)catL;
            float acc0 = 0.f, acc1 = 0.f;
            #pragma unroll
            for (int c = 0; c < 8; ++c) {
                int cc = (c + p) & 7;                // bank-staggered chunk order
                unsigned ua = wo[2 * cc], ub = wo[2 * cc + 1];
                __half2 wa, wb2;
                __builtin_memcpy(&wa, &ua, 4); __builtin_memcpy(&wb2, &ub, 4);
                float wx = __low2float(wa), wy = __high2float(wa);
                float wz = __low2float(wb2), wv = __high2float(wb2);
                float4 v0 = cat4[p * 8 + cc];        // broadcast within 8-lane group
                float4 v1 = cat4[64 + p * 8 + cc];
                acc0 = fmaf(wx, v0.x, fmaf(wy, v0.y, fmaf(wz, v0.z, fmaf(wv, v0.w, acc0))));
                acc1 = fmaf(wx, v1.x, fmaf(wy, v1.y, fmaf(wz, v1.z, fmaf(wv, v1.w, acc1))));
            }
            // reduce over p (lanes stride 8): ror8 (DPP) + xor16 (swz) + xor32
            acc0 = dppadd<0x128>(acc0); acc0 += swz16(acc0); acc0 += __shfl_xor(acc0, 32, 64);
            acc1 = dppadd<0x128>(acc1); acc1 += swz16(acc1); acc1 += __shfl_xor(acc1, 32, 64);
            if (lane < 8) {
                #pragma unroll
                for (int j = 0; j < 2; ++j) {
                    float tot = ((j == 0) ? acc0 : acc1) + boutr;
                    float at = ftanh(tot);
                    float gr = g[j * 512 + oo],       gu = g[j * 512 + 128 + oo];
                    float gn = g[j * 512 + 256 + oo], gs = g[j * 512 + 384 + oo];
                    float rr = fsig(gr), uu = fsig(gu), ss = fsig(gs);
                    float nn = ftanh(gin[j * 128 + oo] + rr * gn);
                    float hv = hid[j * 128 + oo];
                    float curr = fmaf(ss, at, nn);
                    float outv = curr + uu * (hv - curr);
                    hid[j * 128 + oo] = outv;
                    if (t < Tc - 1)
                        updL[j * 128 + oo] = fmaf(ss, ctr[j * 128 + oo], (1.f - ss) * outv);
                    int sj = (j == 0) ? s0 : s1;
                    if (sj == t) dout[(size_t)(blk * 2 + j) * Hc + oo] = outv;
                }
            }
        }
        barlds();
    }
}

// ---------------- host launch ----------------

extern "C" void kernel_launch(void* const* d_in, const int* in_sizes, int n_in,
                              void* d_out, int out_size, void* d_ws, size_t ws_size,
                              hipStream_t stream) {
    const float* feat = (const float*)d_in[0];
    const float* Wih  = (const float*)d_in[1];
    const float* bih  = (const float*)d_in[2];
    const float* Whh  = (const float*)d_in[3];
    const float* bhh  = (const float*)d_in[4];
    const float* Wout = (const float*)d_in[5];
    const float* bout = (const float*)d_in[6];
    const int*   seq  = (const int*)d_in[7];

    char* ws = (char*)d_ws;
    size_t off = 0;
    auto carve = [&](size_t bytes) { char* p = ws + off; off += (bytes + 511) & ~(size_t)511; return p; };
    float*    vbuf   = (float*)   carve((size_t)NEV * Hc * 4);
    int*      head   = (int*)     carve((size_t)NCELL * 4);
    int*      nxt    = (int*)     carve((size_t)NEV * 4);
    int*      cellxy = (int*)     carve((size_t)NEV * 4);
    int*      dep    = (int*)     carve((size_t)NEV * 25 * 4);
    unsigned* flags  = (unsigned*)carve((size_t)NEV * 4);

    hipMemsetAsync(head, 0xFF, (size_t)NCELL * 4, stream);
    hipMemsetAsync(flags, 0, (size_t)NEV * 4, stream);

    k_build<<<(NEV + 255) / 256, 256, 0, stream>>>(feat, head, nxt, cellxy);
    k_resolve<<<(NEV * 25 + 255) / 256, 256, 0, stream>>>(head, nxt, cellxy, dep);

    hipFuncSetAttribute((const void*)step_main,
                        hipFuncAttributeMaxDynamicSharedMemorySize, LDS_BYTES);
    step_main<<<256, 1024, LDS_BYTES, stream>>>(feat, Wih, bih, Whh, bhh, Wout, bout,
                                                seq, dep, vbuf, flags, (float*)d_out);
}